// Round 14
// baseline (303.482 us; speedup 1.0000x reference)
//
#include <hip/hip_runtime.h>

// ---------- types ----------
typedef __attribute__((ext_vector_type(8))) short short8;     // 8 bf16 (4 VGPRs)
typedef __attribute__((ext_vector_type(4))) float floatx4;    // MFMA C/D
typedef __attribute__((ext_vector_type(4))) unsigned int uintx4;

// ---------- fp32 -> packed bf16x2 (RNE) ----------
#if __has_builtin(__builtin_amdgcn_cvt_pk_bf16_f32)
typedef __attribute__((ext_vector_type(2))) __bf16 bf16x2;
__device__ __forceinline__ unsigned int pk_bf16(float a, float b) {
  bf16x2 v = __builtin_amdgcn_cvt_pk_bf16_f32(a, b);
  return __builtin_bit_cast(unsigned int, v);
}
#else
__device__ __forceinline__ unsigned int bf16_1(float f) {
  unsigned int u = __builtin_bit_cast(unsigned int, f);
  return (u + 0x7fffu + ((u >> 16) & 1u)) >> 16;
}
__device__ __forceinline__ unsigned int pk_bf16(float a, float b) {
  return bf16_1(a) | (bf16_1(b) << 16);
}
#endif

#if __has_builtin(__builtin_amdgcn_rcpf)
#define FRCP(x) __builtin_amdgcn_rcpf(x)
#else
#define FRCP(x) (1.0f / (x))
#endif
#if __has_builtin(__builtin_amdgcn_rsqf)
#define FRSQ(x) __builtin_amdgcn_rsqf(x)
#else
#define FRSQ(x) (1.0f / sqrtf(x))
#endif

// Fragment conventions (verified, absmax 3.9e-3):
//   A-frag (16x16x32): lane(ln,quad) holds A[m=ln][k=quad*8+j], j=0..7
//   B-frag:            lane(ln,quad) holds B[n=ln][k=quad*8+j]  (B[k][n]=W[c][r][k], n=r*8+c)
//   C/D:               col=ln, row=quad*4+reg
// Bprep frag id: Fb = ((mod*8 + h)*24 + ks)*4 + nt, n16 = h*4+nt; frag = 64 lanes x 16B.

// ============================================================
// Prepass (v3, verified): LDS-transposed. One block per (mod, n16): reads 16
// weight rows (48 KB) fully coalesced, transposes in LDS, writes 24 KB of
// frags fully coalesced. Grid 96 x 256.
// ============================================================
__global__ __launch_bounds__(256) void prep_w(
    const float* __restrict__ Wi, const float* __restrict__ Wc, const float* __restrict__ Wd,
    const float* __restrict__ bi, const float* __restrict__ bc, const float* __restrict__ bd,
    uintx4* __restrict__ Bprep, float* __restrict__ biasPrep) {
  __shared__ uintx4 Lb[24 * 65];  // idx16 = ks*65 + (q*16 + i); +1 pad per ks row

  const int tid = threadIdx.x;
  const int b = blockIdx.x;          // 0..95
  const int mod = b >> 5;
  const int n16 = b & 31;
  const float* __restrict__ W = (mod == 0) ? Wi : ((mod == 1) ? Wc : Wd);

  const int i = tid >> 4;            // which of the 16 n-rows (i = n & 15)
  const int ct = tid & 15;           // chunk lane within row
  const int n = n16 * 16 + i;
  const int r = n >> 3;
  const int c = n & 7;
  const float* rowp = W + (size_t)(c * 64 + r) * 768;

#pragma unroll
  for (int j = 0; j < 12; ++j) {
    const int k0 = (j * 16 + ct) * 4;          // float offset in row, 16B granule
    float4 f = *(const float4*)(rowp + k0);
    const int ks = k0 >> 5;
    const int q = (k0 >> 3) & 3;
    const int hf = (k0 >> 2) & 1;
    unsigned long long w =
        ((unsigned long long)pk_bf16(f.z, f.w) << 32) | pk_bf16(f.x, f.y);
    ((unsigned long long*)Lb)[((ks * 65 + q * 16 + i) << 1) + hf] = w;
  }
  __syncthreads();

  // write-out: frag = ((mod*8+h)*24 + ks)*4 + nt ; fully coalesced
  const int fragBaseC = ((mod * 8 + (n16 >> 2)) * 24) * 4 + (n16 & 3);
#pragma unroll
  for (int v = 0; v < 6; ++v) {
    const int e = v * 256 + tid;     // 0..1535 = 24 frags x 64 lanes
    const int ks = e >> 6;
    const int l = e & 63;
    Bprep[(size_t)(fragBaseC + ks * 4) * 64 + l] = Lb[ks * 65 + l];
  }

  const int t = b * 256 + tid;
  if (t < 1536) {
    const int m2 = t >> 9;
    const int nn = t & 511;
    const float* bb = (m2 == 0) ? bi : ((m2 == 1) ? bc : bd);
    biasPrep[t] = bb[(nn & 7) * 64 + (nn >> 3)];
  }
}

// ============================================================
// Fused v15: PERSISTENT-B-IN-REGISTERS. Each wave owns n16 (16 cols) and
// holds its ENTIRE K-range of B in 24 uintx4 = 96 VGPRs, loaded once.
// The K-loop has ZERO VMEM: 2 ds_read_b128 (A) + 2 MFMA per step.
// Block = 8 waves (n=128); 8 m-tiles of 32 rows per block, A staged
// full-K (48 KB LDS, R4-verified one-shot STAGE, verified XOR swizzle).
// Epilogue stores overlap next-tile staging between barriers.
// A re-read x4 across n-groups (604 MB) is L3-served (A fits 256MB L3).
// Grid 768 = 12 n-groups x 64 m-chunks, XCD-swizzled. (512,3): demand
// ~143 regs (Breg 96 + stage 16 + a 8 + acc 8 + addr) <= 168.
// ============================================================
#define LOADA(aa, kk)                                                        \
  {                                                                          \
    _Pragma("unroll") for (int mt = 0; mt < 2; ++mt)                         \
        aa[mt] = Afr[((kk) * 2 + mt) * 64 +                                  \
                     ((ln ^ (((kk) * 4 + quad) & 15)) + (quad << 4))];       \
  }

// stage group g (4 of 12 iters): 32 rows x 768 cols fp32 -> 48 bf16 frags
// (ks*2+mt), slot-XOR swizzled. Compile-time indices, <=4 float4 in flight.
#define STAGEA4(g)                                                           \
  {                                                                          \
    _Pragma("unroll") for (int i = (g)*4; i < (g)*4 + 4; ++i) {              \
      const int idx = i * 2048 + tid * 4;                                    \
      float4 f = *(const float4*)(src + idx);                                \
      const int m = (unsigned)idx / 768u;                                    \
      const int k = idx - m * 768;                                           \
      const int ks = k >> 5;                                                 \
      const int kk = k & 31;                                                 \
      const int qk = kk >> 3;                                                \
      const int jh = (kk >> 2) & 1;                                          \
      const int mt = m >> 4;                                                 \
      const int lnn = m & 15;                                                \
      const int p = (ks * 4 + qk) & 15;                                      \
      const int slot = (lnn ^ p) + (qk << 4);                                \
      unsigned long long w =                                                 \
          ((unsigned long long)pk_bf16(f.z, f.w) << 32) | pk_bf16(f.x, f.y); \
      As64[(((ks * 2 + mt) * 64 + slot) << 1) + jh] = w;                     \
    }                                                                        \
  }

#define STAGE_ALL                          \
  {                                        \
    STAGEA4(0);                            \
    __builtin_amdgcn_sched_barrier(0);     \
    STAGEA4(1);                            \
    __builtin_amdgcn_sched_barrier(0);     \
    STAGEA4(2);                            \
  }

__global__ __launch_bounds__(512, 3) void caps_fused(
    const float* __restrict__ x0, const float* __restrict__ x1, const float* __restrict__ x2,
    const uintx4* __restrict__ Bprep, const float* __restrict__ biasPrep,
    float* __restrict__ out) {
  __shared__ unsigned long long As64[48 * 128];  // 48 frags x 64 slots x 16 B

  const int tid = threadIdx.x;
  // XCD-aware swizzle (768 % 8 == 0 -> bijective); consecutive v on one XCD
  // share ng -> that XCD's L2 serves one ~192 KB B-panel.
  const int bx = blockIdx.x;
  const int v = (bx & 7) * 96 + (bx >> 3);
  const int ng = v >> 6;             // n-group 0..11 (mod, n-quarter)
  const int mchunk = v & 63;         // m-chunk: rows mchunk*256 .. +255
  const int mod = ng >> 2;
  const float* __restrict__ X = (mod == 0) ? x0 : ((mod == 1) ? x1 : x2);

  const int lane = tid & 63;
  const int ln = lane & 15;
  const int quad = lane >> 4;
  const int wv = tid >> 6;           // wave id 0..7
  const int n16 = (ng & 3) * 8 + wv; // wave's n16 slot 0..31 within mod

  const uintx4* Afr = (const uintx4*)As64;
  const float* Xb = X + (size_t)mchunk * 256 * 768;

  // ---- persistent B: 24 frags (96 VGPRs), loaded once ----
  const uintx4* __restrict__ bptr =
      Bprep +
      ((size_t)((mod * 8 + (n16 >> 2)) * 24) * 4 + (size_t)(n16 & 3)) * 64 +
      lane;
  uintx4 Breg[24];
#pragma unroll
  for (int ks = 0; ks < 24; ++ks) Breg[ks] = bptr[ks * 256];  // +4 frags/ks

  const int col0 = mod * 512 + n16 * 16 + ln;
  const float bias = biasPrep[col0];

  // ---- stage tile 0 ----
  {
    const float* src = Xb;
    STAGE_ALL;
  }
  __syncthreads();

#pragma unroll 1
  for (int t = 0; t < 8; ++t) {
    // ---- compute: zero VMEM; 2 ds_read + 2 MFMA per K-step ----
    floatx4 acc[2] = {};
    __builtin_amdgcn_s_setprio(1);
#pragma unroll
    for (int ks = 0; ks < 24; ++ks) {
      uintx4 a[2];
      LOADA(a, ks);
#pragma unroll
      for (int mt = 0; mt < 2; ++mt) {
        acc[mt] = __builtin_amdgcn_mfma_f32_16x16x32_bf16(
            __builtin_bit_cast(short8, a[mt]),
            __builtin_bit_cast(short8, Breg[ks]), acc[mt], 0, 0, 0);
      }
    }
    __builtin_amdgcn_s_setprio(0);
    __syncthreads();                 // all waves done reading As tile t

    if (t < 7) {                     // stage t+1 (overlaps epilogue stores)
      const float* src = Xb + (size_t)(t + 1) * 32 * 768;
      STAGE_ALL;
    }

    // ---- epilogue tile t: bias + squash + store (overlaps staging) ----
    const size_t mrow0 = ((size_t)mchunk * 8 + t) * 32;
#pragma unroll
    for (int mt = 0; mt < 2; ++mt) {
      const size_t rbase = (mrow0 + mt * 16 + quad * 4) * 1536 + col0;
#pragma unroll
      for (int jj = 0; jj < 4; ++jj) {
        float u = acc[mt][jj] + bias;
        float s = u * u;
        s += __shfl_xor(s, 1);
        s += __shfl_xor(s, 2);
        s += __shfl_xor(s, 4);
        float sc = s * FRCP(1.0f + s) * FRSQ(s + 1e-7f);
        out[rbase + (size_t)jj * 1536] = u * sc;
      }
    }

    if (t < 7) __syncthreads();      // stage t+1 complete
  }
}

// ============================================================
extern "C" void kernel_launch(void* const* d_in, const int* in_sizes, int n_in,
                              void* d_out, int out_size, void* d_ws, size_t ws_size,
                              hipStream_t stream) {
  const float* ximg = (const float*)d_in[0];
  const float* xcapt = (const float*)d_in[1];
  const float* xdct = (const float*)d_in[2];
  const float* Wi = (const float*)d_in[3];
  const float* bi = (const float*)d_in[4];
  const float* Wc = (const float*)d_in[5];
  const float* bc = (const float*)d_in[6];
  const float* Wd = (const float*)d_in[7];
  const float* bd = (const float*)d_in[8];

  uintx4* Bprep = (uintx4*)d_ws;                           // 2.25 MiB
  float* biasPrep = (float*)((char*)d_ws + 2304 * 1024);   // 6 KiB

  hipLaunchKernelGGL(prep_w, dim3(96), dim3(256), 0, stream,
                     Wi, Wc, Wd, bi, bc, bd, Bprep, biasPrep);
  hipLaunchKernelGGL(caps_fused, dim3(768), dim3(512), 0, stream,
                     ximg, xcapt, xdct, (const uintx4*)Bprep, biasPrep,
                     (float*)d_out);
}

// Round 15
// 277.789 us; speedup vs baseline: 1.0925x; 1.0925x over previous
//
#include <hip/hip_runtime.h>

// ---------- types ----------
typedef __attribute__((ext_vector_type(8))) short short8;     // 8 bf16 (4 VGPRs)
typedef __attribute__((ext_vector_type(4))) float floatx4;    // MFMA C/D
typedef __attribute__((ext_vector_type(4))) unsigned int uintx4;

// ---------- fp32 -> packed bf16x2 (RNE) ----------
#if __has_builtin(__builtin_amdgcn_cvt_pk_bf16_f32)
typedef __attribute__((ext_vector_type(2))) __bf16 bf16x2;
__device__ __forceinline__ unsigned int pk_bf16(float a, float b) {
  bf16x2 v = __builtin_amdgcn_cvt_pk_bf16_f32(a, b);
  return __builtin_bit_cast(unsigned int, v);
}
#else
__device__ __forceinline__ unsigned int bf16_1(float f) {
  unsigned int u = __builtin_bit_cast(unsigned int, f);
  return (u + 0x7fffu + ((u >> 16) & 1u)) >> 16;
}
__device__ __forceinline__ unsigned int pk_bf16(float a, float b) {
  return bf16_1(a) | (bf16_1(b) << 16);
}
#endif

#if __has_builtin(__builtin_amdgcn_rcpf)
#define FRCP(x) __builtin_amdgcn_rcpf(x)
#else
#define FRCP(x) (1.0f / (x))
#endif
#if __has_builtin(__builtin_amdgcn_rsqf)
#define FRSQ(x) __builtin_amdgcn_rsqf(x)
#else
#define FRSQ(x) (1.0f / sqrtf(x))
#endif

// Fragment conventions (verified, absmax 3.9e-3):
//   A-frag (16x16x32): lane(ln,quad) holds A[m=ln][k=quad*8+j], j=0..7
//   B-frag:            lane(ln,quad) holds B[n=ln][k=quad*8+j]  (B[k][n]=W[c][r][k], n=r*8+c)
//   C/D:               col=ln, row=quad*4+reg
// Bprep frag id: Fb = ((mod*8 + h)*24 + ks)*4 + nt, n16 = h*4+nt; frag = 64 lanes x 16B
// = 1024 contiguous bytes: exactly the global_load_lds base+lane*16 pattern.

// ============================================================
// Prepass (v3, verified): LDS-transposed. One block per (mod, n16): reads 16
// weight rows (48 KB) fully coalesced, transposes in LDS, writes 24 KB of
// frags fully coalesced. Grid 96 x 256.
// ============================================================
__global__ __launch_bounds__(256) void prep_w(
    const float* __restrict__ Wi, const float* __restrict__ Wc, const float* __restrict__ Wd,
    const float* __restrict__ bi, const float* __restrict__ bc, const float* __restrict__ bd,
    uintx4* __restrict__ Bprep, float* __restrict__ biasPrep) {
  __shared__ uintx4 Lb[24 * 65];  // idx16 = ks*65 + (q*16 + i); +1 pad per ks row

  const int tid = threadIdx.x;
  const int b = blockIdx.x;          // 0..95
  const int mod = b >> 5;
  const int n16 = b & 31;
  const float* __restrict__ W = (mod == 0) ? Wi : ((mod == 1) ? Wc : Wd);

  const int i = tid >> 4;            // which of the 16 n-rows (i = n & 15)
  const int ct = tid & 15;           // chunk lane within row
  const int n = n16 * 16 + i;
  const int r = n >> 3;
  const int c = n & 7;
  const float* rowp = W + (size_t)(c * 64 + r) * 768;

#pragma unroll
  for (int j = 0; j < 12; ++j) {
    const int k0 = (j * 16 + ct) * 4;          // float offset in row, 16B granule
    float4 f = *(const float4*)(rowp + k0);
    const int ks = k0 >> 5;
    const int q = (k0 >> 3) & 3;
    const int hf = (k0 >> 2) & 1;
    unsigned long long w =
        ((unsigned long long)pk_bf16(f.z, f.w) << 32) | pk_bf16(f.x, f.y);
    ((unsigned long long*)Lb)[((ks * 65 + q * 16 + i) << 1) + hf] = w;
  }
  __syncthreads();

  // write-out: frag = ((mod*8+h)*24 + ks)*4 + nt ; fully coalesced
  const int fragBaseC = ((mod * 8 + (n16 >> 2)) * 24) * 4 + (n16 & 3);
#pragma unroll
  for (int v = 0; v < 6; ++v) {
    const int e = v * 256 + tid;     // 0..1535 = 24 frags x 64 lanes
    const int ks = e >> 6;
    const int l = e & 63;
    Bprep[(size_t)(fragBaseC + ks * 4) * 64 + l] = Lb[ks * 65 + l];
  }

  const int t = b * 256 + tid;
  if (t < 1536) {
    const int m2 = t >> 9;
    const int nn = t & 511;
    const float* bb = (m2 == 0) ? bi : ((m2 == 1) ? bc : bd);
    biasPrep[t] = bb[(nn & 7) * 64 + (nn >> 3)];
  }
}

// ============================================================
// Fused v16: the guide's verified 2-phase template with B staged via
// global_load_lds (B never touches VGPRs -> per-wave ~60 VGPR + 64 AGPR
// fits (512,4)). m=64, 8 waves (wave wv owns n16 = wv*4..+3), grid 768
// (A read ONCE). LDS 76 KB = A-eighth 12 KB (8 restages) + B dbuf 2x32 KB
// -> 2 blocks/CU resident (152 <= 160 KB): one block's barrier drain
// overlaps the other's compute. Per step k: issue 4 DMA (k+1) -> 4+4
// ds_read (A,B) -> 16 MFMA -> __syncthreads (auto vmcnt/lgkm drain).
// 24 step-barriers + 7 A-restage barriers. No inline asm anywhere.
// ============================================================
#define LOADA(aa, kk)                                                        \
  {                                                                          \
    _Pragma("unroll") for (int mt = 0; mt < 4; ++mt)                         \
        aa[mt] = Afr[((kk) * 4 + mt) * 64 +                                  \
                     ((ln ^ (((kk) * 4 + quad) & 15)) + (quad << 4))];       \
  }

#define LOADB(bb, p_)                                                        \
  {                                                                          \
    _Pragma("unroll") for (int nt = 0; nt < 4; ++nt)                         \
        bb[nt] = Bfr[(p_)*2048 + wv * 256 + nt * 64 + lane];                 \
  }

// issue DMA for step k_: 4 frags of this wave's panel -> B buf parity k_&1.
// global src is per-lane (bG includes lane*16); LDS dest wave-uniform.
#define ISSUE_B(k_)                                                          \
  {                                                                          \
    _Pragma("unroll") for (int nt = 0; nt < 4; ++nt) {                       \
      __builtin_amdgcn_global_load_lds(                                      \
          (const __attribute__((address_space(1))) void*)(bG +               \
              (size_t)(((k_)*4 + nt) * 1024)),                               \
          (__attribute__((address_space(3))) void*)(LB +                     \
              (((k_)&1) * 4096 + wv * 512 + nt * 128)),                      \
          16, 0, 0);                                                         \
    }                                                                        \
  }

#define COMP                                                                 \
  {                                                                          \
    _Pragma("unroll") for (int mt = 0; mt < 4; ++mt) {                       \
      short8 af = __builtin_bit_cast(short8, a[mt]);                         \
      _Pragma("unroll") for (int nt = 0; nt < 4; ++nt)                       \
          acc[mt][nt] = __builtin_amdgcn_mfma_f32_16x16x32_bf16(             \
              af, __builtin_bit_cast(short8, b[nt]), acc[mt][nt], 0, 0, 0);  \
    }                                                                        \
  }

// stage A eighth q_ (0..7): 64 rows x 96 k fp32 -> 12 bf16 frags
// (ksl*4+mt), slot-XOR swizzled (verified formula, local ksl). 3 iters.
#define STAGE_A(q_)                                                          \
  {                                                                          \
    _Pragma("unroll") for (int i = 0; i < 3; ++i) {                          \
      const int idx = i * 2048 + tid * 4;                                    \
      const int m = (unsigned)idx / 96u;                                     \
      const int kl = idx - m * 96;                                           \
      float4 f = *(const float4*)(src + (size_t)m * 768 + (q_)*96 + kl);     \
      const int ksl = kl >> 5;                                               \
      const int kk = kl & 31;                                                \
      const int qk = kk >> 3;                                                \
      const int jh = (kk >> 2) & 1;                                          \
      const int mt = m >> 4;                                                 \
      const int lnn = m & 15;                                                \
      const int p = (ksl * 4 + qk) & 15;                                     \
      const int slot = (lnn ^ p) + (qk << 4);                                \
      As64[(((ksl * 4 + mt) * 64 + slot) << 1) + jh] =                       \
          ((unsigned long long)pk_bf16(f.z, f.w) << 32) | pk_bf16(f.x, f.y); \
    }                                                                        \
  }

__global__ __launch_bounds__(512, 4) void caps_fused(
    const float* __restrict__ x0, const float* __restrict__ x1, const float* __restrict__ x2,
    const uintx4* __restrict__ Bprep, const float* __restrict__ biasPrep,
    float* __restrict__ out) {
  // 76 KB: A eighth = 12 KB (u64 0..1535), B dbuf = 2x32 KB (u64 1536..9727)
  __shared__ __align__(16) unsigned long long As64[9728];
  unsigned long long* LB = As64 + 1536;

  const int tid = threadIdx.x;
  // XCD-aware swizzle (768 % 8 == 0 -> bijective)
  const int bx = blockIdx.x;
  const int v = (bx & 7) * 96 + (bx >> 3);
  const int mod = v >> 8;            // 768 = 3 x 256
  const int bm = v & 255;            // m-tile (64 rows)
  const float* __restrict__ X = (mod == 0) ? x0 : ((mod == 1) ? x1 : x2);

  const int lane = tid & 63;
  const int ln = lane & 15;
  const int quad = lane >> 4;
  const int wv = tid >> 6;  // wave id 0..7: owns n16 = wv*4 .. wv*4+3

  const uintx4* Afr = (const uintx4*)As64;
  const uintx4* Bfr = (const uintx4*)LB;
  // per-lane global base of this wave's B panel (96 frags x 1 KB)
  const char* bG = (const char*)Bprep +
                   (size_t)((mod * 8 + wv) * 96) * 1024 + (size_t)lane * 16;
  const float* src = X + (size_t)bm * 64 * 768;

  floatx4 acc[4][4] = {};

  ISSUE_B(0);                        // DMA B step 0 -> buf0
  STAGE_A(0);
  __syncthreads();                   // A eighth 0 + B step 0 ready

#pragma unroll
  for (int k = 0; k < 24; ++k) {
    if (k > 0 && (k % 3) == 0) {     // A-restage at eighth boundary
      STAGE_A(k / 3);
      __syncthreads();
    }
    if (k + 1 < 24) ISSUE_B(k + 1);  // DMA next step's B -> other buf
    uintx4 a[4], b[4];
    LOADA(a, k % 3);
    LOADB(b, k & 1);
    __builtin_amdgcn_s_setprio(1);
    COMP;
    __builtin_amdgcn_s_setprio(0);
    __syncthreads();                 // drains DMA (k+1) + frees buf k&1
  }

  // ---- epilogue: bias + squash (8 consecutive n cols = 8 lanes) + store ----
  const int col0 = mod * 512 + wv * 64 + ln;
  float bias[4];
#pragma unroll
  for (int nt = 0; nt < 4; ++nt) bias[nt] = biasPrep[col0 + nt * 16];

#pragma unroll
  for (int mt = 0; mt < 4; ++mt) {
    const size_t rbase = (size_t)(bm * 64 + mt * 16 + quad * 4) * 1536;
#pragma unroll
    for (int nt = 0; nt < 4; ++nt) {
      float* op = out + rbase + col0 + nt * 16;
#pragma unroll
      for (int jj = 0; jj < 4; ++jj) {
        float u = acc[mt][nt][jj] + bias[nt];
        float s = u * u;
        s += __shfl_xor(s, 1);
        s += __shfl_xor(s, 2);
        s += __shfl_xor(s, 4);
        float sc = s * FRCP(1.0f + s) * FRSQ(s + 1e-7f);
        op[(size_t)jj * 1536] = u * sc;
      }
    }
  }
}

// ============================================================
extern "C" void kernel_launch(void* const* d_in, const int* in_sizes, int n_in,
                              void* d_out, int out_size, void* d_ws, size_t ws_size,
                              hipStream_t stream) {
  const float* ximg = (const float*)d_in[0];
  const float* xcapt = (const float*)d_in[1];
  const float* xdct = (const float*)d_in[2];
  const float* Wi = (const float*)d_in[3];
  const float* bi = (const float*)d_in[4];
  const float* Wc = (const float*)d_in[5];
  const float* bc = (const float*)d_in[6];
  const float* Wd = (const float*)d_in[7];
  const float* bd = (const float*)d_in[8];

  uintx4* Bprep = (uintx4*)d_ws;                           // 2.25 MiB
  float* biasPrep = (float*)((char*)d_ws + 2304 * 1024);   // 6 KiB

  hipLaunchKernelGGL(prep_w, dim3(96), dim3(256), 0, stream,
                     Wi, Wc, Wd, bi, bc, bd, Bprep, biasPrep);
  hipLaunchKernelGGL(caps_fused, dim3(768), dim3(512), 0, stream,
                     ximg, xcapt, xdct, (const uintx4*)Bprep, biasPrep,
                     (float*)d_out);
}

// Round 16
// 266.033 us; speedup vs baseline: 1.1408x; 1.0442x over previous
//
#include <hip/hip_runtime.h>

// ---------- types ----------
typedef __attribute__((ext_vector_type(8))) short short8;     // 8 bf16 (4 VGPRs)
typedef __attribute__((ext_vector_type(4))) float floatx4;    // MFMA C/D
typedef __attribute__((ext_vector_type(4))) unsigned int uintx4;

// ---------- fp32 -> packed bf16x2 (RNE) ----------
#if __has_builtin(__builtin_amdgcn_cvt_pk_bf16_f32)
typedef __attribute__((ext_vector_type(2))) __bf16 bf16x2;
__device__ __forceinline__ unsigned int pk_bf16(float a, float b) {
  bf16x2 v = __builtin_amdgcn_cvt_pk_bf16_f32(a, b);
  return __builtin_bit_cast(unsigned int, v);
}
#else
__device__ __forceinline__ unsigned int bf16_1(float f) {
  unsigned int u = __builtin_bit_cast(unsigned int, f);
  return (u + 0x7fffu + ((u >> 16) & 1u)) >> 16;
}
__device__ __forceinline__ unsigned int pk_bf16(float a, float b) {
  return bf16_1(a) | (bf16_1(b) << 16);
}
#endif

#if __has_builtin(__builtin_amdgcn_rcpf)
#define FRCP(x) __builtin_amdgcn_rcpf(x)
#else
#define FRCP(x) (1.0f / (x))
#endif
#if __has_builtin(__builtin_amdgcn_rsqf)
#define FRSQ(x) __builtin_amdgcn_rsqf(x)
#else
#define FRSQ(x) (1.0f / sqrtf(x))
#endif

// Fragment conventions (verified, absmax 3.9e-3):
//   A-frag (16x16x32): lane(ln,quad) holds A[m=ln][k=quad*8+j], j=0..7
//   B-frag:            lane(ln,quad) holds B[n=ln][k=quad*8+j]  (B[k][n]=W[c][r][k], n=r*8+c)
//   C/D:               col=ln, row=quad*4+reg
// Bprep frag id: Fb = ((mod*8 + h)*24 + ks)*4 + nt, n16 = h*4+nt; frag = 64 lanes x 16B.

// ============================================================
// Prepass (v3, verified): LDS-transposed. One block per (mod, n16): reads 16
// weight rows (48 KB) fully coalesced, transposes in LDS, writes 24 KB of
// frags fully coalesced. Grid 96 x 256.
// ============================================================
__global__ __launch_bounds__(256) void prep_w(
    const float* __restrict__ Wi, const float* __restrict__ Wc, const float* __restrict__ Wd,
    const float* __restrict__ bi, const float* __restrict__ bc, const float* __restrict__ bd,
    uintx4* __restrict__ Bprep, float* __restrict__ biasPrep) {
  __shared__ uintx4 Lb[24 * 65];  // idx16 = ks*65 + (q*16 + i); +1 pad per ks row

  const int tid = threadIdx.x;
  const int b = blockIdx.x;          // 0..95
  const int mod = b >> 5;
  const int n16 = b & 31;
  const float* __restrict__ W = (mod == 0) ? Wi : ((mod == 1) ? Wc : Wd);

  const int i = tid >> 4;            // which of the 16 n-rows (i = n & 15)
  const int ct = tid & 15;           // chunk lane within row
  const int n = n16 * 16 + i;
  const int r = n >> 3;
  const int c = n & 7;
  const float* rowp = W + (size_t)(c * 64 + r) * 768;

#pragma unroll
  for (int j = 0; j < 12; ++j) {
    const int k0 = (j * 16 + ct) * 4;          // float offset in row, 16B granule
    float4 f = *(const float4*)(rowp + k0);
    const int ks = k0 >> 5;
    const int q = (k0 >> 3) & 3;
    const int hf = (k0 >> 2) & 1;
    unsigned long long w =
        ((unsigned long long)pk_bf16(f.z, f.w) << 32) | pk_bf16(f.x, f.y);
    ((unsigned long long*)Lb)[((ks * 65 + q * 16 + i) << 1) + hf] = w;
  }
  __syncthreads();

  // write-out: frag = ((mod*8+h)*24 + ks)*4 + nt ; fully coalesced
  const int fragBaseC = ((mod * 8 + (n16 >> 2)) * 24) * 4 + (n16 & 3);
#pragma unroll
  for (int v = 0; v < 6; ++v) {
    const int e = v * 256 + tid;     // 0..1535 = 24 frags x 64 lanes
    const int ks = e >> 6;
    const int l = e & 63;
    Bprep[(size_t)(fragBaseC + ks * 4) * 64 + l] = Lb[ks * 65 + l];
  }

  const int t = b * 256 + tid;
  if (t < 1536) {
    const int m2 = t >> 9;
    const int nn = t & 511;
    const float* bb = (m2 == 0) ? bi : ((m2 == 1) ? bc : bd);
    biasPrep[t] = bb[(nn & 7) * 64 + (nn >> 3)];
  }
}

// ============================================================
// Fused v12 (R11, session best: caps 110.5 us, total 268.3 us).
// m-tile 64 halves per-CU B-bytes; __launch_bounds__(512,3) -> 168 unified
// regs/wave fits acc 64 (AGPR) + asm-pinned b 32 + a 16 + stage 16 + addr
// with no scratch (measured: VGPR 84, WRITE = output only).
// K-split staging: two 48 KB halves; depth-2 inline-asm B pipeline with
// counted vmcnt (never drains mid-loop). Grid 768 = 3 mods x 256 m-tiles
// (exactly 3 balanced rounds over 256 CUs), XCD-swizzled for B L2 locality.
//
// STRUCTURAL CEILING NOTE (17 experiments): caps time is invariant under
// ILP depth, occupancy 22-57%, B bytes/instructions +-2x, B path
// (VGPR/DMA/persistent), and 4 tile shapes. Binding constraint is
// capacity-forced residency: 64-AGPR acc + any working B-path needs
// ~124-148 regs/wave -> 1 barrier-locked block/CU -> phase-serial latency
// exposed. All escapes measured or priced negative (spills at (256,5),
// (512,4)+stage, (512,8); LDS-B costs > stall removed; bf16-A prepass
// EV-negative).
// ============================================================
#define LOADA(aa, kk)                                                        \
  {                                                                          \
    _Pragma("unroll") for (int mt = 0; mt < 4; ++mt)                         \
        aa[mt] = Afr[((kk) * 4 + mt) * 64 +                                  \
                     ((ln ^ (((kk) * 4 + quad) & 15)) + (quad << 4))];       \
  }

// 4 B-frags of one global K-step: base + {0,1024,2048,3072} bytes
#define ASMB(bb, gg)                                                         \
  {                                                                          \
    const unsigned long long _ad = bAddr + (unsigned long long)(gg)*4096ull; \
    asm volatile("global_load_dwordx4 %0, %4, off\n\t"                       \
                 "global_load_dwordx4 %1, %4, off offset:1024\n\t"           \
                 "global_load_dwordx4 %2, %4, off offset:2048\n\t"           \
                 "global_load_dwordx4 %3, %4, off offset:3072"               \
                 : "=&v"(bb[0]), "=&v"(bb[1]), "=&v"(bb[2]), "=&v"(bb[3])    \
                 : "v"(_ad));                                                \
  }

#define WAITB(N)                                   \
  do {                                             \
    asm volatile("s_waitcnt vmcnt(" #N ")");       \
    __builtin_amdgcn_sched_barrier(0);             \
  } while (0)

#define COMP(aa, bb)                                                     \
  {                                                                      \
    _Pragma("unroll") for (int mt = 0; mt < 4; ++mt)                     \
    {                                                                    \
      short8 af = __builtin_bit_cast(short8, aa[mt]);                    \
      _Pragma("unroll") for (int nt = 0; nt < 4; ++nt)                   \
          acc[mt][nt] = __builtin_amdgcn_mfma_f32_16x16x32_bf16(         \
              af, __builtin_bit_cast(short8, bb[nt]), acc[mt][nt], 0, 0, \
              0);                                                        \
    }                                                                    \
  }

// stage group g (4 of 12 iterations) of one K-half: fully unrolled,
// compile-time indices; <=4 float4 in flight within a group. (R8-verified)
#define STAGE4(h2, g)                                                        \
  {                                                                          \
    _Pragma("unroll") for (int i = (g)*4; i < (g)*4 + 4; ++i) {              \
      const int idx = i * 2048 + tid * 4;                                    \
      const int m = (unsigned)idx / 384u;                                    \
      const int kl = idx - m * 384;                                          \
      float4 f = *(const float4*)(src + (size_t)m * 768 + (h2)*384 + kl);    \
      const int ks2 = kl >> 5;                                               \
      const int kk = kl & 31;                                                \
      const int qk = kk >> 3;                                                \
      const int jh = (kk >> 2) & 1;                                          \
      const int mt = m >> 4;                                                 \
      const int lnn = m & 15;                                                \
      const int p = (ks2 * 4 + qk) & 15;                                     \
      const int slot = (lnn ^ p) + (qk << 4);                                \
      unsigned long long w =                                                 \
          ((unsigned long long)pk_bf16(f.z, f.w) << 32) | pk_bf16(f.x, f.y); \
      As64[(((ks2 * 4 + mt) * 64 + slot) << 1) + jh] = w;                    \
    }                                                                        \
  }

#define STAGE(h2)                          \
  {                                        \
    STAGE4(h2, 0);                         \
    __builtin_amdgcn_sched_barrier(0);     \
    STAGE4(h2, 1);                         \
    __builtin_amdgcn_sched_barrier(0);     \
    STAGE4(h2, 2);                         \
  }

__global__ __launch_bounds__(512, 3) void caps_fused(
    const float* __restrict__ x0, const float* __restrict__ x1, const float* __restrict__ x2,
    const uintx4* __restrict__ Bprep, const float* __restrict__ biasPrep,
    float* __restrict__ out) {
  __shared__ unsigned long long As64[48 * 128];  // 48 frags x 64 slots x 16 B

  const int tid = threadIdx.x;
  // XCD-aware swizzle (768 % 8 == 0 -> bijective)
  const int bx = blockIdx.x;
  const int v = (bx & 7) * 96 + (bx >> 3);
  const int mod = v >> 8;            // 768 = 3 x 256
  const int bm = v & 255;            // m-tile (64 rows)
  const float* __restrict__ X = (mod == 0) ? x0 : ((mod == 1) ? x1 : x2);

  const int lane = tid & 63;
  const int ln = lane & 15;
  const int quad = lane >> 4;
  const int wv = tid >> 6;  // wave id 0..7: owns h = wv (n16 = wv*4 + nt)

  const uintx4* Afr = (const uintx4*)As64;
  const uintx4* __restrict__ bbase =
      Bprep + (size_t)((mod * 8 + wv) * 24) * 4 * 64 + lane;
  const unsigned long long bAddr = (unsigned long long)bbase;
  const float* src = X + (size_t)bm * 64 * 768;

  floatx4 acc[4][4] = {};
  uintx4 a[4], b[2][4];

  // ---- prefetch B steps 0,1 (oldest in queue; retired by first use) ----
  ASMB(b[0], 0);
  ASMB(b[1], 1);

  STAGE(0);
  __syncthreads();                   // As half-0 ready

  LOADA(a, 0);
  // ---- half 0: global steps 0..11 ----
#pragma unroll
  for (int k = 0; k < 12; ++k) {
    WAITB(4);                        // group k retired; 1 group in flight
    __builtin_amdgcn_s_setprio(1);
    COMP(a, b[k & 1]);
    __builtin_amdgcn_s_setprio(0);
    if (k < 11) LOADA(a, k + 1);     // SSA anti-dep: after COMP consumed a
    ASMB(b[k & 1], k + 2);           // groups 12,13 issued at k=10,11
  }
  __syncthreads();                   // all waves done reading As half-0
  STAGE(1);
  __syncthreads();                   // As half-1 ready (stage loads are newer
                                     // than g12,g13; in-order vmcnt retirement
                                     // keeps compiler + WAITB counts correct)

  LOADA(a, 0);
  // ---- half 1: global steps 12..23 ----
#pragma unroll
  for (int k = 0; k < 12; ++k) {
    if (k == 11) {
      WAITB(0);
    } else {
      WAITB(4);                      // no-op for k<=1 (queue drained), exact after
    }
    __builtin_amdgcn_s_setprio(1);
    COMP(a, b[k & 1]);
    __builtin_amdgcn_s_setprio(0);
    if (k < 11) LOADA(a, k + 1);
    if (k < 10) ASMB(b[k & 1], 14 + k);  // groups 14..23
  }

  // ---- epilogue: bias + squash (8 consecutive n cols = 8 lanes) + store ----
  const int col0 = mod * 512 + wv * 64 + ln;
  float bias[4];
#pragma unroll
  for (int nt = 0; nt < 4; ++nt) bias[nt] = biasPrep[col0 + nt * 16];

#pragma unroll
  for (int mt = 0; mt < 4; ++mt) {
    const size_t rbase = (size_t)(bm * 64 + mt * 16 + quad * 4) * 1536;
#pragma unroll
    for (int nt = 0; nt < 4; ++nt) {
      float* op = out + rbase + col0 + nt * 16;
#pragma unroll
      for (int jj = 0; jj < 4; ++jj) {
        float u = acc[mt][nt][jj] + bias[nt];
        float s = u * u;
        s += __shfl_xor(s, 1);
        s += __shfl_xor(s, 2);
        s += __shfl_xor(s, 4);
        float sc = s * FRCP(1.0f + s) * FRSQ(s + 1e-7f);
        op[(size_t)jj * 1536] = u * sc;
      }
    }
  }
}

// ============================================================
extern "C" void kernel_launch(void* const* d_in, const int* in_sizes, int n_in,
                              void* d_out, int out_size, void* d_ws, size_t ws_size,
                              hipStream_t stream) {
  const float* ximg = (const float*)d_in[0];
  const float* xcapt = (const float*)d_in[1];
  const float* xdct = (const float*)d_in[2];
  const float* Wi = (const float*)d_in[3];
  const float* bi = (const float*)d_in[4];
  const float* Wc = (const float*)d_in[5];
  const float* bc = (const float*)d_in[6];
  const float* Wd = (const float*)d_in[7];
  const float* bd = (const float*)d_in[8];

  uintx4* Bprep = (uintx4*)d_ws;                           // 2.25 MiB
  float* biasPrep = (float*)((char*)d_ws + 2304 * 1024);   // 6 KiB

  hipLaunchKernelGGL(prep_w, dim3(96), dim3(256), 0, stream,
                     Wi, Wc, Wd, bi, bc, bd, Bprep, biasPrep);
  hipLaunchKernelGGL(caps_fused, dim3(768), dim3(512), 0, stream,
                     ximg, xcapt, xdct, (const uintx4*)Bprep, biasPrep,
                     (float*)d_out);
}